// Round 7
// baseline (159.256 us; speedup 1.0000x reference)
//
#include <hip/hip_runtime.h>
#include <hip/hip_bf16.h>
#include <stdint.h>

// out[b,n,o] = sum_t x[b,n,t] * (sum_g y[b,g]*w[g,o,t]*mask[o,t]) + bias[o]
// B=32 N=256 T=1024 O=1024 G=8.  bf16 MFMA path (absmax 0.031 vs thr 0.154).
//
//  R15: prep SPLIT into mix_kernel + cvt_kernel for isolated counters, and mix
//       pipelined: 512 blocks x 2 o-values, o1's 9 loads issued BEFORE o0's
//       32-iter b-loop (load latency hides under ~2500cyc of compute+stores).
//       Evidence: store width/layout/occupancy/VMEM-count all varied across
//       R1-R14, mix invariant ~2.7 TB/s -> last untested mechanisms are
//       mix<->cvt interference and load-phase serialization.
//  K2 gemm (R5 best, unchanged): [B][WSTRIDE] Wb, grid (b,tm,tn) XCD=b%8,
//       mfma_32x32x16, 2x2 waves 64x64, 128x128 tile, BK=64, dbuf, swizzle.
//       Gemm is at its memory roofline (~28us vs 208MB/6.3TB/s = 33us naive).

#define B_ 32
#define N_ 256
#define T_ 1024
#define O_ 1024
#define G_ 8

#define WSTRIDE ((size_t)(O_ * T_ + 2048))   // padded b-slice stride, elems

#define BM 128
#define BN 128
#define BK 64            // elems; LDS row = 128 B = 8 x 16 B chunks
#define BUFSZ (BM * BK)  // 8192 elems = 16 KiB

typedef __attribute__((__ext_vector_type__(8)))  __bf16 bf16x8;
typedef __attribute__((__ext_vector_type__(16))) float  f32x16;

__device__ __forceinline__ unsigned short f2bf(float f) {
    union { float f; uint32_t u; } v; v.f = f;
    uint32_t u = v.u;
    uint32_t r = (u + 0x7fffu + ((u >> 16) & 1u)) >> 16;  // RNE
    return (unsigned short)r;
}

__device__ __forceinline__ uint4 pack8(const float* a) {
    uint4 r;
    r.x = (uint32_t)f2bf(a[0]) | ((uint32_t)f2bf(a[1]) << 16);
    r.y = (uint32_t)f2bf(a[2]) | ((uint32_t)f2bf(a[3]) << 16);
    r.z = (uint32_t)f2bf(a[4]) | ((uint32_t)f2bf(a[5]) << 16);
    r.w = (uint32_t)f2bf(a[6]) | ((uint32_t)f2bf(a[7]) << 16);
    return r;
}

// --- K1a: mix.  512 blocks x 2 o-values, software-pipelined.
__global__ __launch_bounds__(256) void mix_kernel(
    const float* __restrict__ w,     // [G,O,T]
    const float* __restrict__ mask,  // [O,T]
    const float* __restrict__ y,     // [B,G]
    unsigned short* __restrict__ Wb) // [B][WSTRIDE] bf16 (padded)
{
    const int tid = threadIdx.x;
    __shared__ float ys[B_ * G_];          // 1 KiB
    ys[tid] = y[tid];
    __syncthreads();

    const int o0 = blockIdx.x;             // 0..511
    const int o1 = blockIdx.x + 512;       // 512..1023
    const int t  = tid << 2;               // 256 thr x 4t = 1024
    const int bph = blockIdx.x & (B_ - 1);

    // --- o0 loads + masked weights
    const float4 m0 = *(const float4*)(mask + (size_t)o0 * T_ + t);
    float wv0[G_][4];
#pragma unroll
    for (int g = 0; g < G_; ++g) {
        const float4 a = *(const float4*)(w + ((size_t)g * O_ + o0) * T_ + t);
        wv0[g][0] = a.x * m0.x; wv0[g][1] = a.y * m0.y;
        wv0[g][2] = a.z * m0.z; wv0[g][3] = a.w * m0.w;
    }

    // --- issue o1 loads EARLY (consumed only after o0's b-loop)
    const float4 m1 = *(const float4*)(mask + (size_t)o1 * T_ + t);
    float4 wraw[G_];
#pragma unroll
    for (int g = 0; g < G_; ++g)
        wraw[g] = *(const float4*)(w + ((size_t)g * O_ + o1) * T_ + t);

    // --- o0 b-loop
    {
        unsigned short* dst = Wb + (size_t)o0 * T_ + t;
#pragma unroll 4
        for (int bi = 0; bi < B_; ++bi) {
            const int b = (bi + bph) & (B_ - 1);
            const float4 y0 = *(const float4*)(ys + b * G_);
            const float4 y1 = *(const float4*)(ys + b * G_ + 4);
            const float yv[G_] = {y0.x, y0.y, y0.z, y0.w, y1.x, y1.y, y1.z, y1.w};
            float acc[4] = {};
#pragma unroll
            for (int g = 0; g < G_; ++g)
#pragma unroll
                for (int j = 0; j < 4; ++j)
                    acc[j] += yv[g] * wv0[g][j];
            ushort4 pk;
            pk.x = f2bf(acc[0]); pk.y = f2bf(acc[1]);
            pk.z = f2bf(acc[2]); pk.w = f2bf(acc[3]);
            *(ushort4*)(dst + (size_t)b * WSTRIDE) = pk;
        }
    }

    // --- o1 masked weights (loads landed during o0 loop) + b-loop
    float wv1[G_][4];
#pragma unroll
    for (int g = 0; g < G_; ++g) {
        wv1[g][0] = wraw[g].x * m1.x; wv1[g][1] = wraw[g].y * m1.y;
        wv1[g][2] = wraw[g].z * m1.z; wv1[g][3] = wraw[g].w * m1.w;
    }
    {
        unsigned short* dst = Wb + (size_t)o1 * T_ + t;
#pragma unroll 4
        for (int bi = 0; bi < B_; ++bi) {
            const int b = (bi + bph) & (B_ - 1);
            const float4 y0 = *(const float4*)(ys + b * G_);
            const float4 y1 = *(const float4*)(ys + b * G_ + 4);
            const float yv[G_] = {y0.x, y0.y, y0.z, y0.w, y1.x, y1.y, y1.z, y1.w};
            float acc[4] = {};
#pragma unroll
            for (int g = 0; g < G_; ++g)
#pragma unroll
                for (int j = 0; j < 4; ++j)
                    acc[j] += yv[g] * wv1[g][j];
            ushort4 pk;
            pk.x = f2bf(acc[0]); pk.y = f2bf(acc[1]);
            pk.z = f2bf(acc[2]); pk.w = f2bf(acc[3]);
            *(ushort4*)(dst + (size_t)b * WSTRIDE) = pk;
        }
    }
}

// --- K1b: cvt.  x f32 -> xb bf16 (pure stream).
__global__ __launch_bounds__(256) void cvt_kernel(
    const float* __restrict__ x,     // [B,N,T]
    unsigned short* __restrict__ xb) // [B,N,T] bf16
{
    const int i = blockIdx.x * 256 + threadIdx.x;
    const float4* x4 = (const float4*)x;
    uint4* o4 = (uint4*)xb;
#pragma unroll
    for (int j = 0; j < 4; ++j) {
        const size_t f4 = (size_t)j * 524288 + (size_t)i * 2;
        const float4 a = x4[f4];
        const float4 b = x4[f4 + 1];
        const float v[8] = {a.x, a.y, a.z, a.w, b.x, b.y, b.z, b.w};
        o4[(size_t)j * 262144 + i] = pack8(v);
    }
}

__device__ __forceinline__ void load16_to_lds(const unsigned short* g, unsigned short* l) {
    __builtin_amdgcn_global_load_lds(
        (const __attribute__((address_space(1))) unsigned char*)g,
        (__attribute__((address_space(3))) unsigned char*)l,
        16, 0, 0);
}

// --- K2: batched GEMM, C = A . B^T, K-major bf16, mfma_32x32x16.
// 256 threads = 4 waves (2m x 2n), wave tile 64x64 = 2x2 of 32x32, acc 2x2xf32x16.
// A-frag: m=lane&31, k=(lane>>5)*8+j; B-frag symmetric.
// C/D: col=lane&31, row=(reg&3)+8*(reg>>2)+4*(lane>>5) [m74/m101].
// LDS chunk c of row r holds global chunk (c ^ (r&7)) -> conflict-free b128.
// Grid = (b, tm, tn): XCD = linear%8 = b%8 -> same-b blocks colocate on an XCD.
__global__ __launch_bounds__(256, 2) void gemm_kernel(
    const unsigned short* __restrict__ xb,   // [B][N_][T_] bf16
    const unsigned short* __restrict__ Wb,   // [B][WSTRIDE] bf16 (padded)
    const float* __restrict__ bias,          // [O_]
    float* __restrict__ out)                 // [B][N_][O_] f32
{
    __shared__ __align__(16) unsigned short lA[2 * BUFSZ];  // 32 KiB
    __shared__ __align__(16) unsigned short lB[2 * BUFSZ];  // 32 KiB

    const int b  = blockIdx.x;   // 0..31  (XCD = b%8)
    const int tm = blockIdx.y;   // 0..1   (n tiles)
    const int tn = blockIdx.z;   // 0..7   (o tiles)

    const int tid  = threadIdx.x;
    const int lane = tid & 63;
    const int wave = tid >> 6;          // 0..3
    const int wm   = (wave >> 1) * 64;
    const int wn   = (wave & 1) * 64;

    const unsigned short* Ab = xb + (size_t)b * N_ * T_ + (size_t)(tm * BM) * T_;
    const unsigned short* Bb = Wb + (size_t)b * WSTRIDE + (size_t)(tn * BN) * T_;

    // staging (256 thr): round i: LDS elem tid*8 + i*2048 -> row tid/8 + i*32
    const int srow   = tid >> 3;                 // 0..31
    const int schunk = (tid & 7) ^ (srow & 7);   // (i*32)&7==0 -> round-invariant
    const unsigned short* ga0 = Ab + (size_t)srow * T_ + schunk * 8;
    const unsigned short* gb0 = Bb + (size_t)srow * T_ + schunk * 8;

#define STAGE(buf, kt)                                                          \
    {                                                                           \
        unsigned short* lad = lA + (buf) * BUFSZ + tid * 8;                     \
        unsigned short* lbd = lB + (buf) * BUFSZ + tid * 8;                     \
        _Pragma("unroll")                                                       \
        for (int i_ = 0; i_ < 4; ++i_) {                                        \
            load16_to_lds(ga0 + (kt) + (size_t)(i_ * 32) * T_, lad + i_ * 2048);\
            load16_to_lds(gb0 + (kt) + (size_t)(i_ * 32) * T_, lbd + i_ * 2048);\
        }                                                                       \
    }

    f32x16 acc[2][2] = {};

    const int fr   = lane & 31;      // fragment row within 32
    const int half = lane >> 5;      // k-half 0/1 (8 elems each)
    const int sw   = fr & 7;         // swizzle term (wm, mi*32 are multiples of 8)

#define COMPUTE(buf)                                                            \
    {                                                                           \
        const unsigned short* la = lA + (buf) * BUFSZ;                          \
        const unsigned short* lb = lB + (buf) * BUFSZ;                          \
        _Pragma("unroll")                                                       \
        for (int ks = 0; ks < 4; ++ks) {                                        \
            const int cp = (((ks * 2 + half)) ^ sw) * 8;                        \
            bf16x8 afr[2], bfr[2];                                              \
            _Pragma("unroll")                                                   \
            for (int i_ = 0; i_ < 2; ++i_)                                      \
                afr[i_] = *(const bf16x8*)(la + (wm + i_ * 32 + fr) * BK + cp); \
            _Pragma("unroll")                                                   \
            for (int i_ = 0; i_ < 2; ++i_)                                      \
                bfr[i_] = *(const bf16x8*)(lb + (wn + i_ * 32 + fr) * BK + cp); \
            _Pragma("unroll")                                                   \
            for (int mi = 0; mi < 2; ++mi)                                      \
                _Pragma("unroll")                                               \
                for (int ni = 0; ni < 2; ++ni)                                  \
                    acc[mi][ni] = __builtin_amdgcn_mfma_f32_32x32x16_bf16(      \
                        afr[mi], bfr[ni], acc[mi][ni], 0, 0, 0);                \
        }                                                                       \
    }

    STAGE(0, 0)
    for (int kt = 0; kt < T_; kt += 2 * BK) {
        __syncthreads();                       // buf0(kt) staged
        STAGE(1, kt + BK)                      // prefetch buf1
        COMPUTE(0)
        __syncthreads();                       // buf1 staged; buf0 reads done
        if (kt + 2 * BK < T_) STAGE(0, kt + 2 * BK)
        COMPUTE(1)
    }

    // Epilogue: D col=lane&31, row=(reg&3)+8*(reg>>2)+4*(lane>>5)  + bias.
    float* outb = out + (size_t)b * N_ * O_ + (size_t)(tm * BM) * O_ + (tn * BN);
    const int cn = lane & 31;
    const int rb = (lane >> 5) * 4;
#pragma unroll
    for (int ni = 0; ni < 2; ++ni) {
        const int col = wn + ni * 32 + cn;
        const float bv = bias[tn * BN + col];
#pragma unroll
        for (int mi = 0; mi < 2; ++mi) {
#pragma unroll
            for (int r = 0; r < 16; ++r) {
                const int row = wm + mi * 32 + rb + (r & 3) + 8 * (r >> 2);
                outb[(size_t)row * O_ + col] = acc[mi][ni][r] + bv;
            }
        }
    }
}

// --- Fallback (ws too small): correct fp32 path.
__global__ __launch_bounds__(256) void naive_kernel(
    const float* __restrict__ x, const float* __restrict__ y,
    const float* __restrict__ w, const float* __restrict__ mask,
    const float* __restrict__ bias, float* __restrict__ out)
{
    const int oc = blockIdx.x & 3;
    const int n  = (blockIdx.x >> 2) & (N_ - 1);
    const int b  = blockIdx.x >> 10;

    __shared__ float xs[T_];
    __shared__ float ys[G_];
    const float* xrow = x + ((size_t)b * N_ + n) * T_;
    for (int i = threadIdx.x; i < T_ / 4; i += 256)
        ((float4*)xs)[i] = ((const float4*)xrow)[i];
    if (threadIdx.x < G_) ys[threadIdx.x] = y[b * G_ + threadIdx.x];
    __syncthreads();

    const int o = oc * 256 + threadIdx.x;
    float acc = 0.f;
    for (int t = 0; t < T_; t += 4) {
        const float4 m4 = *(const float4*)(mask + (size_t)o * T_ + t);
        float4 s = {0.f, 0.f, 0.f, 0.f};
#pragma unroll
        for (int g = 0; g < G_; ++g) {
            const float4 w4 = *(const float4*)(w + ((size_t)g * O_ + o) * T_ + t);
            const float yv = ys[g];
            s.x += yv * w4.x; s.y += yv * w4.y; s.z += yv * w4.z; s.w += yv * w4.w;
        }
        acc += xs[t] * m4.x * s.x + xs[t + 1] * m4.y * s.y
             + xs[t + 2] * m4.z * s.z + xs[t + 3] * m4.w * s.w;
    }
    out[((size_t)b * N_ + n) * O_ + o] = acc + bias[o];
}

extern "C" void kernel_launch(void* const* d_in, const int* in_sizes, int n_in,
                              void* d_out, int out_size, void* d_ws, size_t ws_size,
                              hipStream_t stream) {
    const float* x    = (const float*)d_in[0];
    const float* y    = (const float*)d_in[1];
    const float* w    = (const float*)d_in[2];
    const float* mask = (const float*)d_in[3];
    const float* bias = (const float*)d_in[4];
    float* out = (float*)d_out;

    const size_t wb_bytes = (size_t)B_ * WSTRIDE * sizeof(unsigned short); // 64 MiB + 128 KB
    const size_t xb_bytes = (size_t)B_ * N_ * T_ * sizeof(unsigned short); // 16 MiB

    if (ws_size >= wb_bytes + xb_bytes) {
        unsigned short* Wb = (unsigned short*)d_ws;
        unsigned short* xb = (unsigned short*)((char*)d_ws + wb_bytes);
        mix_kernel<<<512, 256, 0, stream>>>(w, mask, y, Wb);
        cvt_kernel<<<1024, 256, 0, stream>>>(x, xb);
        dim3 grid(B_, N_ / BM, O_ / BN);   // x=b -> XCD=b%8: A,B L2-resident
        gemm_kernel<<<grid, 256, 0, stream>>>(xb, Wb, bias, out);
    } else {
        naive_kernel<<<B_ * N_ * (O_ / 256), 256, 0, stream>>>(x, y, w, mask, bias, out);
    }
}

// Round 8
// 157.826 us; speedup vs baseline: 1.0091x; 1.0091x over previous
//
#include <hip/hip_runtime.h>
#include <hip/hip_bf16.h>
#include <stdint.h>

// out[b,n,o] = sum_t x[b,n,t] * (sum_g y[b,g]*w[g,o,t]*mask[o,t]) + bias[o]
// B=32 N=256 T=1024 O=1024 G=8.  bf16 MFMA path (absmax 0.031 vs thr 0.154).
//
//  R16 = R5 (best, 150.6us) + NONTEMPORAL stores in prep (single variable).
//       Mix wall ledger: store width / layout / occupancy / VMEM count /
//       load overlap all varied R1-R15, mix invariant ~2.7 TB/s with ideal
//       WRITE_SIZE.  Last mechanism: L2 write-allocate thrash (80 MB dirty
//       through 4 MiB/XCD L2).  nt stores bypass L2 (fill does 6.5 TB/s).
//       Gemm unaffected: its Wb/xb reads come from L3 (cross-XCD) anyway.
//  R7 lesson: splitting mix/cvt lost their overlap (-9us) -> keep fused.
//  Fusing mix into gemm: dead on arithmetic (32-64x w re-read from L2).

#define B_ 32
#define N_ 256
#define T_ 1024
#define O_ 1024
#define G_ 8

#define WSTRIDE ((size_t)(O_ * T_ + 2048))   // padded b-slice stride, elems

#define BM 128
#define BN 128
#define BK 64            // elems; LDS row = 128 B = 8 x 16 B chunks
#define BUFSZ (BM * BK)  // 8192 elems = 16 KiB

typedef __attribute__((__ext_vector_type__(8)))  __bf16 bf16x8;
typedef __attribute__((__ext_vector_type__(16))) float  f32x16;
typedef __attribute__((__ext_vector_type__(2)))  uint32_t u32x2;
typedef __attribute__((__ext_vector_type__(4)))  uint32_t u32x4;

__device__ __forceinline__ unsigned short f2bf(float f) {
    union { float f; uint32_t u; } v; v.f = f;
    uint32_t u = v.u;
    uint32_t r = (u + 0x7fffu + ((u >> 16) & 1u)) >> 16;  // RNE
    return (unsigned short)r;
}

__device__ __forceinline__ u32x4 pack8(const float* a) {
    u32x4 r;
    r.x = (uint32_t)f2bf(a[0]) | ((uint32_t)f2bf(a[1]) << 16);
    r.y = (uint32_t)f2bf(a[2]) | ((uint32_t)f2bf(a[3]) << 16);
    r.z = (uint32_t)f2bf(a[4]) | ((uint32_t)f2bf(a[5]) << 16);
    r.w = (uint32_t)f2bf(a[6]) | ((uint32_t)f2bf(a[7]) << 16);
    return r;
}

#define MIXB 1024   // O*T/4 threads / 256
#define CVTB 1024   // 262144 threads, 8 float4 each

// --- K1: fused prologue (R5 structure + nontemporal stores).
__global__ __launch_bounds__(256) void prep_kernel(
    const float* __restrict__ w,     // [G,O,T]
    const float* __restrict__ mask,  // [O,T]
    const float* __restrict__ y,     // [B,G]
    const float* __restrict__ x,     // [B,N,T]
    unsigned short* __restrict__ Wb, // [B][WSTRIDE] bf16 (padded)
    unsigned short* __restrict__ xb) // [B,N,T] bf16
{
    const int tid = threadIdx.x;
    if (blockIdx.x < MIXB) {
        __shared__ float ys[B_ * G_];          // 1 KiB
        ys[tid] = y[tid];
        __syncthreads();

        const int idx = blockIdx.x * 256 + tid;   // over O*T/4
        const int o   = idx >> 8;
        const int t   = (idx & 255) << 2;

        const float4 m4 = *(const float4*)(mask + (size_t)o * T_ + t);

        float wv[G_][4];
#pragma unroll
        for (int g = 0; g < G_; ++g) {
            const float4 a = *(const float4*)(w + ((size_t)g * O_ + o) * T_ + t);
            wv[g][0] = a.x * m4.x; wv[g][1] = a.y * m4.y;
            wv[g][2] = a.z * m4.z; wv[g][3] = a.w * m4.w;
        }
        unsigned short* dst = Wb + (size_t)o * T_ + t;
        const int bph = blockIdx.x & (B_ - 1);
#pragma unroll 4
        for (int bi = 0; bi < B_; ++bi) {
            const int b = (bi + bph) & (B_ - 1);
            const float4 y0 = *(const float4*)(ys + b * G_);      // LDS broadcast
            const float4 y1 = *(const float4*)(ys + b * G_ + 4);
            const float yv[G_] = {y0.x, y0.y, y0.z, y0.w, y1.x, y1.y, y1.z, y1.w};
            float acc[4] = {};
#pragma unroll
            for (int g = 0; g < G_; ++g)
#pragma unroll
                for (int j = 0; j < 4; ++j)
                    acc[j] += yv[g] * wv[g][j];
            u32x2 pk;
            pk.x = (uint32_t)f2bf(acc[0]) | ((uint32_t)f2bf(acc[1]) << 16);
            pk.y = (uint32_t)f2bf(acc[2]) | ((uint32_t)f2bf(acc[3]) << 16);
            __builtin_nontemporal_store(pk, (u32x2*)(dst + (size_t)b * WSTRIDE));
        }
    } else {
        const int i = (blockIdx.x - MIXB) * 256 + tid;
        const float4* x4 = (const float4*)x;
        u32x4* o4 = (u32x4*)xb;
#pragma unroll
        for (int j = 0; j < 4; ++j) {
            const size_t f4 = (size_t)j * 524288 + (size_t)i * 2;
            const float4 a = x4[f4];
            const float4 b = x4[f4 + 1];
            const float v[8] = {a.x, a.y, a.z, a.w, b.x, b.y, b.z, b.w};
            __builtin_nontemporal_store(pack8(v), o4 + (size_t)j * 262144 + i);
        }
    }
}

__device__ __forceinline__ void load16_to_lds(const unsigned short* g, unsigned short* l) {
    __builtin_amdgcn_global_load_lds(
        (const __attribute__((address_space(1))) unsigned char*)g,
        (__attribute__((address_space(3))) unsigned char*)l,
        16, 0, 0);
}

// --- K2: batched GEMM, C = A . B^T, K-major bf16, mfma_32x32x16.
// 256 threads = 4 waves (2m x 2n), wave tile 64x64 = 2x2 of 32x32, acc 2x2xf32x16.
// A-frag: m=lane&31, k=(lane>>5)*8+j; B-frag symmetric.
// C/D: col=lane&31, row=(reg&3)+8*(reg>>2)+4*(lane>>5) [m74/m101].
// LDS chunk c of row r holds global chunk (c ^ (r&7)) -> conflict-free b128.
// Grid = (b, tm, tn): XCD = linear%8 = b%8 -> same-b blocks colocate on an XCD.
__global__ __launch_bounds__(256, 2) void gemm_kernel(
    const unsigned short* __restrict__ xb,   // [B][N_][T_] bf16
    const unsigned short* __restrict__ Wb,   // [B][WSTRIDE] bf16 (padded)
    const float* __restrict__ bias,          // [O_]
    float* __restrict__ out)                 // [B][N_][O_] f32
{
    __shared__ __align__(16) unsigned short lA[2 * BUFSZ];  // 32 KiB
    __shared__ __align__(16) unsigned short lB[2 * BUFSZ];  // 32 KiB

    const int b  = blockIdx.x;   // 0..31  (XCD = b%8)
    const int tm = blockIdx.y;   // 0..1   (n tiles)
    const int tn = blockIdx.z;   // 0..7   (o tiles)

    const int tid  = threadIdx.x;
    const int lane = tid & 63;
    const int wave = tid >> 6;          // 0..3
    const int wm   = (wave >> 1) * 64;
    const int wn   = (wave & 1) * 64;

    const unsigned short* Ab = xb + (size_t)b * N_ * T_ + (size_t)(tm * BM) * T_;
    const unsigned short* Bb = Wb + (size_t)b * WSTRIDE + (size_t)(tn * BN) * T_;

    // staging (256 thr): round i: LDS elem tid*8 + i*2048 -> row tid/8 + i*32
    const int srow   = tid >> 3;                 // 0..31
    const int schunk = (tid & 7) ^ (srow & 7);   // (i*32)&7==0 -> round-invariant
    const unsigned short* ga0 = Ab + (size_t)srow * T_ + schunk * 8;
    const unsigned short* gb0 = Bb + (size_t)srow * T_ + schunk * 8;

#define STAGE(buf, kt)                                                          \
    {                                                                           \
        unsigned short* lad = lA + (buf) * BUFSZ + tid * 8;                     \
        unsigned short* lbd = lB + (buf) * BUFSZ + tid * 8;                     \
        _Pragma("unroll")                                                       \
        for (int i_ = 0; i_ < 4; ++i_) {                                        \
            load16_to_lds(ga0 + (kt) + (size_t)(i_ * 32) * T_, lad + i_ * 2048);\
            load16_to_lds(gb0 + (kt) + (size_t)(i_ * 32) * T_, lbd + i_ * 2048);\
        }                                                                       \
    }

    f32x16 acc[2][2] = {};

    const int fr   = lane & 31;      // fragment row within 32
    const int half = lane >> 5;      // k-half 0/1 (8 elems each)
    const int sw   = fr & 7;         // swizzle term (wm, mi*32 are multiples of 8)

#define COMPUTE(buf)                                                            \
    {                                                                           \
        const unsigned short* la = lA + (buf) * BUFSZ;                          \
        const unsigned short* lb = lB + (buf) * BUFSZ;                          \
        _Pragma("unroll")                                                       \
        for (int ks = 0; ks < 4; ++ks) {                                        \
            const int cp = (((ks * 2 + half)) ^ sw) * 8;                        \
            bf16x8 afr[2], bfr[2];                                              \
            _Pragma("unroll")                                                   \
            for (int i_ = 0; i_ < 2; ++i_)                                      \
                afr[i_] = *(const bf16x8*)(la + (wm + i_ * 32 + fr) * BK + cp); \
            _Pragma("unroll")                                                   \
            for (int i_ = 0; i_ < 2; ++i_)                                      \
                bfr[i_] = *(const bf16x8*)(lb + (wn + i_ * 32 + fr) * BK + cp); \
            _Pragma("unroll")                                                   \
            for (int mi = 0; mi < 2; ++mi)                                      \
                _Pragma("unroll")                                               \
                for (int ni = 0; ni < 2; ++ni)                                  \
                    acc[mi][ni] = __builtin_amdgcn_mfma_f32_32x32x16_bf16(      \
                        afr[mi], bfr[ni], acc[mi][ni], 0, 0, 0);                \
        }                                                                       \
    }

    STAGE(0, 0)
    for (int kt = 0; kt < T_; kt += 2 * BK) {
        __syncthreads();                       // buf0(kt) staged
        STAGE(1, kt + BK)                      // prefetch buf1
        COMPUTE(0)
        __syncthreads();                       // buf1 staged; buf0 reads done
        if (kt + 2 * BK < T_) STAGE(0, kt + 2 * BK)
        COMPUTE(1)
    }

    // Epilogue: D col=lane&31, row=(reg&3)+8*(reg>>2)+4*(lane>>5)  + bias.
    float* outb = out + (size_t)b * N_ * O_ + (size_t)(tm * BM) * O_ + (tn * BN);
    const int cn = lane & 31;
    const int rb = (lane >> 5) * 4;
#pragma unroll
    for (int ni = 0; ni < 2; ++ni) {
        const int col = wn + ni * 32 + cn;
        const float bv = bias[tn * BN + col];
#pragma unroll
        for (int mi = 0; mi < 2; ++mi) {
#pragma unroll
            for (int r = 0; r < 16; ++r) {
                const int row = wm + mi * 32 + rb + (r & 3) + 8 * (r >> 2);
                outb[(size_t)row * O_ + col] = acc[mi][ni][r] + bv;
            }
        }
    }
}

// --- Fallback (ws too small): correct fp32 path.
__global__ __launch_bounds__(256) void naive_kernel(
    const float* __restrict__ x, const float* __restrict__ y,
    const float* __restrict__ w, const float* __restrict__ mask,
    const float* __restrict__ bias, float* __restrict__ out)
{
    const int oc = blockIdx.x & 3;
    const int n  = (blockIdx.x >> 2) & (N_ - 1);
    const int b  = blockIdx.x >> 10;

    __shared__ float xs[T_];
    __shared__ float ys[G_];
    const float* xrow = x + ((size_t)b * N_ + n) * T_;
    for (int i = threadIdx.x; i < T_ / 4; i += 256)
        ((float4*)xs)[i] = ((const float4*)xrow)[i];
    if (threadIdx.x < G_) ys[threadIdx.x] = y[b * G_ + threadIdx.x];
    __syncthreads();

    const int o = oc * 256 + threadIdx.x;
    float acc = 0.f;
    for (int t = 0; t < T_; t += 4) {
        const float4 m4 = *(const float4*)(mask + (size_t)o * T_ + t);
        float4 s = {0.f, 0.f, 0.f, 0.f};
#pragma unroll
        for (int g = 0; g < G_; ++g) {
            const float4 w4 = *(const float4*)(w + ((size_t)g * O_ + o) * T_ + t);
            const float yv = ys[g];
            s.x += yv * w4.x; s.y += yv * w4.y; s.z += yv * w4.z; s.w += yv * w4.w;
        }
        acc += xs[t] * m4.x * s.x + xs[t + 1] * m4.y * s.y
             + xs[t + 2] * m4.z * s.z + xs[t + 3] * m4.w * s.w;
    }
    out[((size_t)b * N_ + n) * O_ + o] = acc + bias[o];
}

extern "C" void kernel_launch(void* const* d_in, const int* in_sizes, int n_in,
                              void* d_out, int out_size, void* d_ws, size_t ws_size,
                              hipStream_t stream) {
    const float* x    = (const float*)d_in[0];
    const float* y    = (const float*)d_in[1];
    const float* w    = (const float*)d_in[2];
    const float* mask = (const float*)d_in[3];
    const float* bias = (const float*)d_in[4];
    float* out = (float*)d_out;

    const size_t wb_bytes = (size_t)B_ * WSTRIDE * sizeof(unsigned short); // 64 MiB + 128 KB
    const size_t xb_bytes = (size_t)B_ * N_ * T_ * sizeof(unsigned short); // 16 MiB

    if (ws_size >= wb_bytes + xb_bytes) {
        unsigned short* Wb = (unsigned short*)d_ws;
        unsigned short* xb = (unsigned short*)((char*)d_ws + wb_bytes);
        prep_kernel<<<MIXB + CVTB, 256, 0, stream>>>(w, mask, y, x, Wb, xb);
        dim3 grid(B_, N_ / BM, O_ / BN);   // x=b -> XCD=b%8: A,B L2-resident
        gemm_kernel<<<grid, 256, 0, stream>>>(xb, Wb, bias, out);
    } else {
        naive_kernel<<<B_ * N_ * (O_ / 256), 256, 0, stream>>>(x, y, w, mask, bias, out);
    }
}

// Round 9
// 149.519 us; speedup vs baseline: 1.0651x; 1.0556x over previous
//
#include <hip/hip_runtime.h>
#include <hip/hip_bf16.h>
#include <stdint.h>

// out[b,n,o] = sum_t x[b,n,t] * (sum_g y[b,g]*w[g,o,t]*mask[o,t]) + bias[o]
// B=32 N=256 T=1024 O=1024 G=8.  bf16 MFMA path (absmax 0.031 vs thr 0.154).
//
//  R17: prep = R5 exact (best: 42.5us; nt-stores reverted, they cooled L3 for
//       gemm).  gemm REPIPELINED: R8 profile showed 43us @ MfmaUtil 14%,
//       VALU 6%, HBM 1.7 TB/s, occ 17% -> barrier-drain latency-bound
//       (__syncthreads = vmcnt(0) drain of all 8 in-flight global_load_lds
//       per k-tile).  Now raw s_barrier + counted vmcnt(8): tile t+1's loads
//       stay in flight across barriers (T3/T4 pattern, guide m218: +38-73%).
//       Race audit: BARRIER after COMPUTE(c) = all waves' ds_reads of buf c
//       done (lgkm drained pre-MFMA) before STAGE overwrites c; VMCNT(8) +
//       BARRIER = every wave's tile-t loads landed before any wave reads.

#define B_ 32
#define N_ 256
#define T_ 1024
#define O_ 1024
#define G_ 8

#define WSTRIDE ((size_t)(O_ * T_ + 2048))   // padded b-slice stride, elems

#define BM 128
#define BN 128
#define BK 64            // elems; LDS row = 128 B = 8 x 16 B chunks
#define BUFSZ (BM * BK)  // 8192 elems = 16 KiB
#define NT (T_ / BK)     // 16 k-tiles

typedef __attribute__((__ext_vector_type__(8)))  __bf16 bf16x8;
typedef __attribute__((__ext_vector_type__(16))) float  f32x16;

__device__ __forceinline__ unsigned short f2bf(float f) {
    union { float f; uint32_t u; } v; v.f = f;
    uint32_t u = v.u;
    uint32_t r = (u + 0x7fffu + ((u >> 16) & 1u)) >> 16;  // RNE
    return (unsigned short)r;
}

__device__ __forceinline__ uint4 pack8(const float* a) {
    uint4 r;
    r.x = (uint32_t)f2bf(a[0]) | ((uint32_t)f2bf(a[1]) << 16);
    r.y = (uint32_t)f2bf(a[2]) | ((uint32_t)f2bf(a[3]) << 16);
    r.z = (uint32_t)f2bf(a[4]) | ((uint32_t)f2bf(a[5]) << 16);
    r.w = (uint32_t)f2bf(a[6]) | ((uint32_t)f2bf(a[7]) << 16);
    return r;
}

#define MIXB 1024   // O*T/4 threads / 256
#define CVTB 1024   // 262144 threads, 8 float4 each

// --- K1: fused prologue (R5 exact).
__global__ __launch_bounds__(256) void prep_kernel(
    const float* __restrict__ w,     // [G,O,T]
    const float* __restrict__ mask,  // [O,T]
    const float* __restrict__ y,     // [B,G]
    const float* __restrict__ x,     // [B,N,T]
    unsigned short* __restrict__ Wb, // [B][WSTRIDE] bf16 (padded)
    unsigned short* __restrict__ xb) // [B,N,T] bf16
{
    const int tid = threadIdx.x;
    if (blockIdx.x < MIXB) {
        __shared__ float ys[B_ * G_];          // 1 KiB
        ys[tid] = y[tid];
        __syncthreads();

        const int idx = blockIdx.x * 256 + tid;   // over O*T/4
        const int o   = idx >> 8;
        const int t   = (idx & 255) << 2;

        const float4 m4 = *(const float4*)(mask + (size_t)o * T_ + t);

        float wv[G_][4];
#pragma unroll
        for (int g = 0; g < G_; ++g) {
            const float4 a = *(const float4*)(w + ((size_t)g * O_ + o) * T_ + t);
            wv[g][0] = a.x * m4.x; wv[g][1] = a.y * m4.y;
            wv[g][2] = a.z * m4.z; wv[g][3] = a.w * m4.w;
        }
        unsigned short* dst = Wb + (size_t)o * T_ + t;
        const int bph = blockIdx.x & (B_ - 1);
#pragma unroll 4
        for (int bi = 0; bi < B_; ++bi) {
            const int b = (bi + bph) & (B_ - 1);
            const float4 y0 = *(const float4*)(ys + b * G_);      // LDS broadcast
            const float4 y1 = *(const float4*)(ys + b * G_ + 4);
            const float yv[G_] = {y0.x, y0.y, y0.z, y0.w, y1.x, y1.y, y1.z, y1.w};
            float acc[4] = {};
#pragma unroll
            for (int g = 0; g < G_; ++g)
#pragma unroll
                for (int j = 0; j < 4; ++j)
                    acc[j] += yv[g] * wv[g][j];
            ushort4 pk;
            pk.x = f2bf(acc[0]); pk.y = f2bf(acc[1]);
            pk.z = f2bf(acc[2]); pk.w = f2bf(acc[3]);
            *(ushort4*)(dst + (size_t)b * WSTRIDE) = pk;
        }
    } else {
        const int i = (blockIdx.x - MIXB) * 256 + tid;
        const float4* x4 = (const float4*)x;
        uint4* o4 = (uint4*)xb;
#pragma unroll
        for (int j = 0; j < 4; ++j) {
            const size_t f4 = (size_t)j * 524288 + (size_t)i * 2;
            const float4 a = x4[f4];
            const float4 b = x4[f4 + 1];
            const float v[8] = {a.x, a.y, a.z, a.w, b.x, b.y, b.z, b.w};
            o4[(size_t)j * 262144 + i] = pack8(v);
        }
    }
}

__device__ __forceinline__ void load16_to_lds(const unsigned short* g, unsigned short* l) {
    __builtin_amdgcn_global_load_lds(
        (const __attribute__((address_space(1))) unsigned char*)g,
        (__attribute__((address_space(3))) unsigned char*)l,
        16, 0, 0);
}

#define VMCNT_8 asm volatile("s_waitcnt vmcnt(8)" ::: "memory")
#define VMCNT_0 asm volatile("s_waitcnt vmcnt(0)" ::: "memory")
#define BARRIER asm volatile("s_barrier" ::: "memory")

// --- K2: batched GEMM, C = A . B^T, K-major bf16, mfma_32x32x16.
// 256 threads = 4 waves (2m x 2n), wave tile 64x64 = 2x2 of 32x32, acc 2x2xf32x16.
// A-frag: m=lane&31, k=(lane>>5)*8+j; B-frag symmetric.
// C/D: col=lane&31, row=(reg&3)+8*(reg>>2)+4*(lane>>5) [m74/m101].
// LDS chunk c of row r holds global chunk (c ^ (r&7)) -> swizzled b128.
// Grid = (b, tm, tn): XCD = linear%8 = b%8 -> same-b blocks colocate on an XCD.
// K-loop: counted-vmcnt double-buffer; 8 loads/tile stay in flight across
// raw s_barriers (no vmcnt(0) drain in steady state).
__global__ __launch_bounds__(256, 2) void gemm_kernel(
    const unsigned short* __restrict__ xb,   // [B][N_][T_] bf16
    const unsigned short* __restrict__ Wb,   // [B][WSTRIDE] bf16 (padded)
    const float* __restrict__ bias,          // [O_]
    float* __restrict__ out)                 // [B][N_][O_] f32
{
    __shared__ __align__(16) unsigned short lA[2 * BUFSZ];  // 32 KiB
    __shared__ __align__(16) unsigned short lB[2 * BUFSZ];  // 32 KiB

    const int b  = blockIdx.x;   // 0..31  (XCD = b%8)
    const int tm = blockIdx.y;   // 0..1   (n tiles)
    const int tn = blockIdx.z;   // 0..7   (o tiles)

    const int tid  = threadIdx.x;
    const int lane = tid & 63;
    const int wave = tid >> 6;          // 0..3
    const int wm   = (wave >> 1) * 64;
    const int wn   = (wave & 1) * 64;

    const unsigned short* Ab = xb + (size_t)b * N_ * T_ + (size_t)(tm * BM) * T_;
    const unsigned short* Bb = Wb + (size_t)b * WSTRIDE + (size_t)(tn * BN) * T_;

    // staging (256 thr): round i: LDS elem tid*8 + i*2048 -> row tid/8 + i*32
    const int srow   = tid >> 3;                 // 0..31
    const int schunk = (tid & 7) ^ (srow & 7);   // (i*32)&7==0 -> round-invariant
    const unsigned short* ga0 = Ab + (size_t)srow * T_ + schunk * 8;
    const unsigned short* gb0 = Bb + (size_t)srow * T_ + schunk * 8;

#define STAGE(buf, kt)                                                          \
    {                                                                           \
        unsigned short* lad = lA + (buf) * BUFSZ + tid * 8;                     \
        unsigned short* lbd = lB + (buf) * BUFSZ + tid * 8;                     \
        _Pragma("unroll")                                                       \
        for (int i_ = 0; i_ < 4; ++i_) {                                        \
            load16_to_lds(ga0 + (kt) + (size_t)(i_ * 32) * T_, lad + i_ * 2048);\
            load16_to_lds(gb0 + (kt) + (size_t)(i_ * 32) * T_, lbd + i_ * 2048);\
        }                                                                       \
    }

    f32x16 acc[2][2] = {};

    const int fr   = lane & 31;      // fragment row within 32
    const int half = lane >> 5;      // k-half 0/1 (8 elems each)
    const int sw   = fr & 7;         // swizzle term (wm, mi*32 are multiples of 8)

#define COMPUTE(buf)                                                            \
    {                                                                           \
        const unsigned short* la = lA + (buf) * BUFSZ;                          \
        const unsigned short* lb = lB + (buf) * BUFSZ;                          \
        _Pragma("unroll")                                                       \
        for (int ks = 0; ks < 4; ++ks) {                                        \
            const int cp = (((ks * 2 + half)) ^ sw) * 8;                        \
            bf16x8 afr[2], bfr[2];                                              \
            _Pragma("unroll")                                                   \
            for (int i_ = 0; i_ < 2; ++i_)                                      \
                afr[i_] = *(const bf16x8*)(la + (wm + i_ * 32 + fr) * BK + cp); \
            _Pragma("unroll")                                                   \
            for (int i_ = 0; i_ < 2; ++i_)                                      \
                bfr[i_] = *(const bf16x8*)(lb + (wn + i_ * 32 + fr) * BK + cp); \
            _Pragma("unroll")                                                   \
            for (int mi = 0; mi < 2; ++mi)                                      \
                _Pragma("unroll")                                               \
                for (int ni = 0; ni < 2; ++ni)                                  \
                    acc[mi][ni] = __builtin_amdgcn_mfma_f32_32x32x16_bf16(      \
                        afr[mi], bfr[ni], acc[mi][ni], 0, 0, 0);                \
        }                                                                       \
    }

    STAGE(0, 0)
    STAGE(1, BK)
    // steady state: entering iter t, tiles t (8 loads) + t+1 (8 loads) issued.
    // vmcnt(8) completes tile t (oldest 8); t+1's 8 ride across the barriers.
    for (int t = 0; t < NT - 1; ++t) {
        const int c = t & 1;
        VMCNT_8;
        BARRIER;                       // buf c complete on all waves
        COMPUTE(c)
        BARRIER;                       // all waves done reading buf c
        if (t < NT - 2) STAGE(c, (t + 2) * BK)
    }
    VMCNT_0;
    BARRIER;                           // last tile staged everywhere
    COMPUTE(1)

    // Epilogue: D col=lane&31, row=(reg&3)+8*(reg>>2)+4*(lane>>5)  + bias.
    float* outb = out + (size_t)b * N_ * O_ + (size_t)(tm * BM) * O_ + (tn * BN);
    const int cn = lane & 31;
    const int rb = (lane >> 5) * 4;
#pragma unroll
    for (int ni = 0; ni < 2; ++ni) {
        const int col = wn + ni * 32 + cn;
        const float bv = bias[tn * BN + col];
#pragma unroll
        for (int mi = 0; mi < 2; ++mi) {
#pragma unroll
            for (int r = 0; r < 16; ++r) {
                const int row = wm + mi * 32 + rb + (r & 3) + 8 * (r >> 2);
                outb[(size_t)row * O_ + col] = acc[mi][ni][r] + bv;
            }
        }
    }
}

// --- Fallback (ws too small): correct fp32 path.
__global__ __launch_bounds__(256) void naive_kernel(
    const float* __restrict__ x, const float* __restrict__ y,
    const float* __restrict__ w, const float* __restrict__ mask,
    const float* __restrict__ bias, float* __restrict__ out)
{
    const int oc = blockIdx.x & 3;
    const int n  = (blockIdx.x >> 2) & (N_ - 1);
    const int b  = blockIdx.x >> 10;

    __shared__ float xs[T_];
    __shared__ float ys[G_];
    const float* xrow = x + ((size_t)b * N_ + n) * T_;
    for (int i = threadIdx.x; i < T_ / 4; i += 256)
        ((float4*)xs)[i] = ((const float4*)xrow)[i];
    if (threadIdx.x < G_) ys[threadIdx.x] = y[b * G_ + threadIdx.x];
    __syncthreads();

    const int o = oc * 256 + threadIdx.x;
    float acc = 0.f;
    for (int t = 0; t < T_; t += 4) {
        const float4 m4 = *(const float4*)(mask + (size_t)o * T_ + t);
        float4 s = {0.f, 0.f, 0.f, 0.f};
#pragma unroll
        for (int g = 0; g < G_; ++g) {
            const float4 w4 = *(const float4*)(w + ((size_t)g * O_ + o) * T_ + t);
            const float yv = ys[g];
            s.x += yv * w4.x; s.y += yv * w4.y; s.z += yv * w4.z; s.w += yv * w4.w;
        }
        acc += xs[t] * m4.x * s.x + xs[t + 1] * m4.y * s.y
             + xs[t + 2] * m4.z * s.z + xs[t + 3] * m4.w * s.w;
    }
    out[((size_t)b * N_ + n) * O_ + o] = acc + bias[o];
}

extern "C" void kernel_launch(void* const* d_in, const int* in_sizes, int n_in,
                              void* d_out, int out_size, void* d_ws, size_t ws_size,
                              hipStream_t stream) {
    const float* x    = (const float*)d_in[0];
    const float* y    = (const float*)d_in[1];
    const float* w    = (const float*)d_in[2];
    const float* mask = (const float*)d_in[3];
    const float* bias = (const float*)d_in[4];
    float* out = (float*)d_out;

    const size_t wb_bytes = (size_t)B_ * WSTRIDE * sizeof(unsigned short); // 64 MiB + 128 KB
    const size_t xb_bytes = (size_t)B_ * N_ * T_ * sizeof(unsigned short); // 16 MiB

    if (ws_size >= wb_bytes + xb_bytes) {
        unsigned short* Wb = (unsigned short*)d_ws;
        unsigned short* xb = (unsigned short*)((char*)d_ws + wb_bytes);
        prep_kernel<<<MIXB + CVTB, 256, 0, stream>>>(w, mask, y, x, Wb, xb);
        dim3 grid(B_, N_ / BM, O_ / BN);   // x=b -> XCD=b%8: A,B L2-resident
        gemm_kernel<<<grid, 256, 0, stream>>>(xb, Wb, bias, out);
    } else {
        naive_kernel<<<B_ * N_ * (O_ / 256), 256, 0, stream>>>(x, y, w, mask, bias, out);
    }
}